// Round 1
// baseline (407.463 us; speedup 1.0000x reference)
//
#include <hip/hip_runtime.h>
#include <cstdint>

typedef unsigned short u16;
typedef __attribute__((ext_vector_type(8))) short bf16x8;
typedef __attribute__((ext_vector_type(4))) float f32x4;

__device__ __forceinline__ u16 f2b(float x) {
  unsigned u = __float_as_uint(x);
  u += 0x7FFFu + ((u >> 16) & 1u);
  return (u16)(u >> 16);
}

__device__ __forceinline__ void gload16(const void* g, void* l) {
  __builtin_amdgcn_global_load_lds(
      (const __attribute__((address_space(1))) void*)g,
      (__attribute__((address_space(3))) void*)l, 16, 0, 0);
}

// ---------------------------------------------------------------------------
// Core bf16 MFMA mainloop (m97 structure): 128x128 tile, BK=32, 256 threads,
// 4 waves each computing a 64x64 quadrant as 4x4 frags of 16x16x32.
// A is [M,K] row-major (lda), B is [N,K] row-major (ldb): computes A @ B^T.
// Caller passes A,B already offset to the tile origin (tM rows / tN rows).
// ---------------------------------------------------------------------------
__device__ __forceinline__ void mma_pass(const u16* __restrict__ A, int lda,
                                         const u16* __restrict__ B, int ldb,
                                         int K, u16* As, u16* Bs,
                                         f32x4 (&acc)[4][4]) {
  const int tid = threadIdx.x;
  const int wid = tid >> 6, lane = tid & 63;
  const int wr = ((wid >> 1) << 6), wc = ((wid & 1) << 6);
  const int lr = lane & 15, lk = ((lane >> 4) << 3);
  const int sr = tid >> 2, sc = ((tid & 3) << 3);
  const u16* ga = A + (long long)sr * lda + sc;
  const u16* gb = B + (long long)sr * ldb + sc;
  u16* la = As + tid * 8;
  u16* lb = Bs + tid * 8;
  for (int k0 = 0; k0 < K; k0 += 32) {
    gload16(ga, la);
    gload16(ga + (long long)64 * lda, la + 2048);
    gload16(gb, lb);
    gload16(gb + (long long)64 * ldb, lb + 2048);
    ga += 32; gb += 32;
    __syncthreads();
    bf16x8 af[4], bfr[4];
#pragma unroll
    for (int m = 0; m < 4; ++m)
      af[m] = *(const bf16x8*)(As + (wr + m * 16 + lr) * 32 + lk);
#pragma unroll
    for (int n = 0; n < 4; ++n)
      bfr[n] = *(const bf16x8*)(Bs + (wc + n * 16 + lr) * 32 + lk);
#pragma unroll
    for (int m = 0; m < 4; ++m)
#pragma unroll
      for (int n = 0; n < 4; ++n)
        acc[m][n] = __builtin_amdgcn_mfma_f32_16x16x32_bf16(af[m], bfr[n], acc[m][n], 0, 0, 0);
    __syncthreads();
  }
}

// EPI: 0 = QKV (bf16 out, bias select per 1024-col group, Q cols scaled 1/32)
//      1 = theta (bf16 out, cos(pi*sigmoid(acc*preScale + b_t)))
//      2 = plain bf16 out
//      3 = fp32 out + bias
template <int EPI>
__global__ __launch_bounds__(256) void gemm_bt(
    const u16* __restrict__ A, int lda, long long sAz,
    const u16* __restrict__ B, int ldb, long long sBz,
    void* __restrict__ Cv, int ldc, long long sCz, int K,
    const float* __restrict__ bias0, const float* __restrict__ bias1,
    const float* __restrict__ bias2, float preScale) {
  __shared__ u16 As[128 * 32];
  __shared__ u16 Bs[128 * 32];
  const int z = blockIdx.z;
  const int tM = blockIdx.y * 128, tN = blockIdx.x * 128;
  f32x4 acc[4][4] = {};
  mma_pass(A + z * sAz + (long long)tM * lda, lda,
           B + z * sBz + (long long)tN * ldb, ldb, K, As, Bs, acc);
  const int tid = threadIdx.x;
  const int wid = tid >> 6, lane = tid & 63;
  const int wr = ((wid >> 1) << 6), wc = ((wid & 1) << 6);
  const int lr = lane & 15;
  const int rr = ((lane >> 4) << 2);
#pragma unroll
  for (int m = 0; m < 4; ++m) {
#pragma unroll
    for (int n = 0; n < 4; ++n) {
      const int col = tN + wc + n * 16 + lr;
      float badd = 0.f, smul = 1.f;
      if constexpr (EPI == 0) {
        const float* bp = (col < 1024) ? bias0 : ((col < 2048) ? bias1 : bias2);
        badd = bp[col & 1023];
        smul = (col < 1024) ? 0.03125f : 1.0f;
      }
#pragma unroll
      for (int r = 0; r < 4; ++r) {
        const long long row = tM + wr + m * 16 + rr + r;
        float v = acc[m][n][r];
        if constexpr (EPI == 0) {
          ((u16*)Cv)[z * sCz + row * ldc + col] = f2b((v + badd) * smul);
        } else if constexpr (EPI == 1) {
          float t = v * preScale + bias0[col];
          float sg = 1.f / (1.f + __expf(-t));
          ((u16*)Cv)[z * sCz + row * ldc + col] = f2b(cospif(sg));
        } else if constexpr (EPI == 2) {
          ((u16*)Cv)[z * sCz + row * ldc + col] = f2b(v);
        } else {
          ((float*)Cv)[z * sCz + row * ldc + col] = v + bias0[col];
        }
      }
    }
  }
}

// logits = Qs @ K^T + es * (rq @ rk^T), per batch z; fp32 out [2048,2048]
__global__ __launch_bounds__(256) void gemm_scores(
    const u16* __restrict__ QKV, const u16* __restrict__ RQ,
    const u16* __restrict__ RK, float* __restrict__ L,
    const float* __restrict__ esp) {
  __shared__ u16 As[128 * 32];
  __shared__ u16 Bs[128 * 32];
  const int z = blockIdx.z;
  const int tM = blockIdx.y * 128, tN = blockIdx.x * 128;
  const long long zb = (long long)z * 2048;
  const u16* Qs = QKV + zb * 3072;          // cols 0..1023 of QKV rows (Q/32)
  const u16* Km = Qs + 1024;                // cols 1024..2047 (K)
  const u16* rq = RQ + zb * 1024;
  const u16* rk = RK + zb * 1024;
  const float es = esp[0];
  f32x4 acc[4][4] = {};
  // pass 1: quantum term
  mma_pass(rq + (long long)tM * 1024, 1024, rk + (long long)tN * 1024, 1024,
           1024, As, Bs, acc);
#pragma unroll
  for (int m = 0; m < 4; ++m)
#pragma unroll
    for (int n = 0; n < 4; ++n) acc[m][n] *= es;
  // pass 2: classical term (Qs = Q/32 so no extra scale)
  mma_pass(Qs + (long long)tM * 3072, 3072, Km + (long long)tN * 3072, 3072,
           1024, As, Bs, acc);
  float* C = L + (long long)z * 2048 * 2048;
  const int tid = threadIdx.x;
  const int wid = tid >> 6, lane = tid & 63;
  const int wr = ((wid >> 1) << 6), wc = ((wid & 1) << 6);
  const int lr = lane & 15;
  const int rr = ((lane >> 4) << 2);
#pragma unroll
  for (int m = 0; m < 4; ++m)
#pragma unroll
    for (int n = 0; n < 4; ++n) {
      const int col = tN + wc + n * 16 + lr;
#pragma unroll
      for (int r = 0; r < 4; ++r) {
        const long long row = tM + wr + m * 16 + rr + r;
        C[row * 2048 + col] = acc[m][n][r];
      }
    }
}

// row softmax over [8192][2048]: fp32 in-place + bf16 copy
__global__ __launch_bounds__(256) void softmax_rows(float* __restrict__ L,
                                                    u16* __restrict__ AB) {
  const long long row = blockIdx.x;
  float4* p4 = (float4*)(L + row * 2048);
  const int tid = threadIdx.x;
  float4 a = p4[tid], b = p4[tid + 256];
  float m = fmaxf(fmaxf(fmaxf(a.x, a.y), fmaxf(a.z, a.w)),
                  fmaxf(fmaxf(b.x, b.y), fmaxf(b.z, b.w)));
#pragma unroll
  for (int o = 32; o > 0; o >>= 1) m = fmaxf(m, __shfl_xor(m, o));
  __shared__ float rmax[4], rsum[4];
  const int wid = tid >> 6, lane = tid & 63;
  if (lane == 0) rmax[wid] = m;
  __syncthreads();
  m = fmaxf(fmaxf(rmax[0], rmax[1]), fmaxf(rmax[2], rmax[3]));
  a.x = __expf(a.x - m); a.y = __expf(a.y - m);
  a.z = __expf(a.z - m); a.w = __expf(a.w - m);
  b.x = __expf(b.x - m); b.y = __expf(b.y - m);
  b.z = __expf(b.z - m); b.w = __expf(b.w - m);
  float s = a.x + a.y + a.z + a.w + b.x + b.y + b.z + b.w;
#pragma unroll
  for (int o = 32; o > 0; o >>= 1) s += __shfl_xor(s, o);
  if (lane == 0) rsum[wid] = s;
  __syncthreads();
  s = rsum[0] + rsum[1] + rsum[2] + rsum[3];
  const float inv = 1.0f / s;
  a.x *= inv; a.y *= inv; a.z *= inv; a.w *= inv;
  b.x *= inv; b.y *= inv; b.z *= inv; b.w *= inv;
  p4[tid] = a;
  p4[tid + 256] = b;
  ushort4 h0 = make_ushort4(f2b(a.x), f2b(a.y), f2b(a.z), f2b(a.w));
  ushort4 h1 = make_ushort4(f2b(b.x), f2b(b.y), f2b(b.z), f2b(b.w));
  ushort4* o4 = (ushort4*)(AB + row * 2048);
  o4[tid] = h0;
  o4[tid + 256] = h1;
}

__global__ __launch_bounds__(256) void cvt_x(const float* __restrict__ X,
                                             u16* __restrict__ XB) {
  const int i = blockIdx.x * 256 + threadIdx.x;
  float4 v = ((const float4*)X)[i];
  ((ushort4*)XB)[i] = make_ushort4(f2b(v.x), f2b(v.y), f2b(v.z), f2b(v.w));
}

// transpose+convert 5 weight matrices [1024,1024] f32 -> bf16 W^T
__global__ void cvt_w(const float* __restrict__ W0, const float* __restrict__ W1,
                      const float* __restrict__ W2, const float* __restrict__ W3,
                      const float* __restrict__ W4, u16* __restrict__ WT) {
  __shared__ float t[32][33];
  const int z = blockIdx.z;
  const float* W = (z == 0) ? W0 : (z == 1) ? W1 : (z == 2) ? W2 : (z == 3) ? W3 : W4;
  u16* D = WT + (long long)z * 1024 * 1024;
  const int c0 = blockIdx.x * 32, r0 = blockIdx.y * 32;
  const int tx = threadIdx.x, ty = threadIdx.y;
#pragma unroll
  for (int i = 0; i < 4; ++i)
    t[ty + i * 8][tx] = W[(long long)(r0 + ty + i * 8) * 1024 + c0 + tx];
  __syncthreads();
#pragma unroll
  for (int i = 0; i < 4; ++i)
    D[(long long)(c0 + ty + i * 8) * 1024 + r0 + tx] = f2b(t[tx][ty + i * 8]);
}

// V (cols 2048..3071 of QKV, per batch [2048,1024]) -> VT [1024,2048] bf16
__global__ void transpose_v(const u16* __restrict__ QKV, u16* __restrict__ VT) {
  __shared__ u16 t[32][33];
  const int b = blockIdx.z;
  const u16* V = QKV + (long long)b * 2048 * 3072 + 2048;
  u16* O = VT + (long long)b * 1024 * 2048;
  const int d0 = blockIdx.x * 32, s0 = blockIdx.y * 32;
  const int tx = threadIdx.x, ty = threadIdx.y;
#pragma unroll
  for (int i = 0; i < 4; ++i)
    t[ty + i * 8][tx] = V[(long long)(s0 + ty + i * 8) * 3072 + d0 + tx];
  __syncthreads();
#pragma unroll
  for (int i = 0; i < 4; ++i)
    O[(long long)(d0 + ty + i * 8) * 2048 + s0 + tx] = t[tx][ty + i * 8];
}

extern "C" void kernel_launch(void* const* d_in, const int* in_sizes, int n_in,
                              void* d_out, int out_size, void* d_ws,
                              size_t ws_size, hipStream_t stream) {
  const float* x  = (const float*)d_in[0];
  const float* Wq = (const float*)d_in[1];
  const float* bq = (const float*)d_in[2];
  const float* Wk = (const float*)d_in[3];
  const float* bk = (const float*)d_in[4];
  const float* Wv = (const float*)d_in[5];
  const float* bv = (const float*)d_in[6];
  const float* Wt = (const float*)d_in[7];
  const float* bt = (const float*)d_in[8];
  const float* Wo = (const float*)d_in[9];
  const float* bo = (const float*)d_in[10];
  const float* es = (const float*)d_in[11];

  char* ws = (char*)d_ws;
  u16* WT  = (u16*)(ws + 0);           // 5x [1024,1024] bf16 W^T  (10.5 MB)
  u16* XB  = (u16*)(ws + 10485760);    // x bf16 [8192,1024]; later attn@V
  u16* QKV = (u16*)(ws + 27262976);    // [8192,3072] bf16 (Q/32 | K | V)
  u16* RQ  = (u16*)(ws + 77594624);    // [8192,1024] bf16; RQ+RK reused as attn bf16
  u16* RK  = (u16*)(ws + 94371840);
  u16* VT  = (u16*)(ws + 111149056);   // [4][1024,2048] bf16
  u16* ATT = RQ;                       // attn bf16 [8192,2048]
  u16* AV  = XB;                       // attn@V bf16 [8192,1024]
  u16* WtT = WT + 3 * 1048576;
  u16* WoT = WT + 4 * 1048576;

  float* outO = (float*)d_out;         // [4,2048,1024]
  float* outA = outO + 8388608;        // [4,2048,2048] logits -> attn

  cvt_x<<<8192, 256, 0, stream>>>(x, XB);
  cvt_w<<<dim3(32, 32, 5), dim3(32, 8), 0, stream>>>(Wq, Wk, Wv, Wt, Wo, WT);
  // QKV projection (Q stored as (Q+b_q)/32)
  gemm_bt<0><<<dim3(24, 64, 1), 256, 0, stream>>>(
      XB, 1024, 0, WT, 1024, 0, QKV, 3072, 0, 1024, bq, bk, bv, 1.f);
  // r_q / r_k
  gemm_bt<1><<<dim3(8, 64, 1), 256, 0, stream>>>(
      QKV, 3072, 0, WtT, 1024, 0, RQ, 1024, 0, 1024, bt, nullptr, nullptr, 32.f);
  gemm_bt<1><<<dim3(8, 64, 1), 256, 0, stream>>>(
      QKV + 1024, 3072, 0, WtT, 1024, 0, RK, 1024, 0, 1024, bt, nullptr, nullptr, 1.f);
  transpose_v<<<dim3(32, 64, 4), dim3(32, 8), 0, stream>>>(QKV, VT);
  // logits into d_out attn region
  gemm_scores<<<dim3(16, 16, 4), 256, 0, stream>>>(QKV, RQ, RK, outA, es);
  // softmax in-place (fp32) + bf16 copy
  softmax_rows<<<8192, 256, 0, stream>>>(outA, ATT);
  // attn @ V
  gemm_bt<2><<<dim3(8, 16, 4), 256, 0, stream>>>(
      ATT, 2048, 4194304LL, VT, 2048, 2097152LL, AV, 1024, 2097152LL, 2048,
      nullptr, nullptr, nullptr, 1.f);
  // output projection
  gemm_bt<3><<<dim3(8, 64, 1), 256, 0, stream>>>(
      AV, 1024, 0, WoT, 1024, 0, outO, 1024, 0, 1024, bo, nullptr, nullptr, 1.f);
}

// Round 3
// 364.115 us; speedup vs baseline: 1.1191x; 1.1191x over previous
//
#include <hip/hip_runtime.h>
#include <cstdint>

typedef unsigned short u16;
typedef __attribute__((ext_vector_type(8))) short bf16x8;
typedef __attribute__((ext_vector_type(4))) float f32x4;

__device__ __forceinline__ u16 f2b(float x) {
  unsigned u = __float_as_uint(x);
  u += 0x7FFFu + ((u >> 16) & 1u);
  return (u16)(u >> 16);
}

__device__ __forceinline__ void gload16(const void* g, void* l) {
  __builtin_amdgcn_global_load_lds(
      (const __attribute__((address_space(1))) void*)g,
      (__attribute__((address_space(3))) void*)l, 16, 0, 0);
}

// row-dependent chunk swizzle: spreads a column of 16B chunks over 8 banks
__device__ __forceinline__ int swz(int r) { return (r & 3) ^ ((r >> 2) & 3); }

// stage a 256x32 bf16 tile (16 KB) from global (row-major, ld) into LDS.
// LDS dest is linear (chunk P = j*512+tid); global src is inverse-swizzled so
// reads with the swizzled address see the right data (both-sides rule, m231).
__device__ __forceinline__ void stageA(const u16* __restrict__ G, int ld,
                                       int k0, u16* L, int tid) {
#pragma unroll
  for (int j = 0; j < 2; ++j) {
    const int P = j * 512 + tid;
    const int r = P >> 2;
    const int cl = (P & 3) ^ swz(r);
    gload16(G + (long long)r * ld + k0 + cl * 8, L + P * 8);
  }
}
// stage a 128x32 bf16 tile (8 KB)
__device__ __forceinline__ void stageB128(const u16* __restrict__ G, int ld,
                                          int k0, u16* L, int tid) {
  const int P = tid;
  const int r = P >> 2;
  const int cl = (P & 3) ^ swz(r);
  gload16(G + (long long)r * ld + k0 + cl * 8, L + P * 8);
}

// ---------------------------------------------------------------------------
// 256x(NREP*64) tile GEMM, BK=32, 512 threads (8 waves, 2Mx4N), 4-buffer LDS,
// prefetch depth 3, counted vmcnt, one barrier/K-step.
// Computes C = A @ B^T; A [M,K] row-major lda, B [N,K] row-major ldb.
// EPI: 0=QKV split (Qcat/Kcat/Vb)  1=theta->cat halves  2=bf16  3=f32+bias
//      4=f32 plain
// ---------------------------------------------------------------------------
template <int EPI, int NREP>
__global__ __launch_bounds__(512, 2) void g256(
    const u16* __restrict__ A, int lda, long long sAz,
    const u16* __restrict__ B, int ldb, long long sBz,
    void* __restrict__ C0, void* __restrict__ C1, void* __restrict__ C2,
    int ldc, long long sCz, int K,
    const float* __restrict__ b0, const float* __restrict__ b1,
    const float* __restrict__ b2, float preScale, const float* __restrict__ esp) {
  constexpr int BN = NREP * 64;
  constexpr int ASZ = 8192;          // u16 per A slice (256*32)
  constexpr int BSZ = NREP * 2048;   // u16 per B slice
  constexpr int BUF = ASZ + BSZ;
  __shared__ __align__(16) u16 lds[4 * BUF];

  const int z = blockIdx.z;
  const long long tM = (long long)blockIdx.y * 256;
  const long long tN = (long long)blockIdx.x * BN;
  const u16* Ab = A + z * sAz + tM * lda;
  const u16* Bb = B + z * sBz + tN * ldb;
  const int tid = threadIdx.x;
  const int NT = K >> 5;

#pragma unroll
  for (int t = 0; t < 3; ++t) {
    u16* Lb = lds + t * BUF;
    stageA(Ab, lda, t * 32, Lb, tid);
    if constexpr (NREP == 4) stageA(Bb, ldb, t * 32, Lb + ASZ, tid);
    else stageB128(Bb, ldb, t * 32, Lb + ASZ, tid);
  }

  f32x4 acc[8][NREP] = {};
  const int wid = tid >> 6, lane = tid & 63;
  const int wr = (wid >> 2) * 128;       // A panel base row
  const int wc = (wid & 3) * (BN / 4);   // B panel base row (C col)
  const int lr = lane & 15;
  const int cA = lane >> 4;              // k-chunk 0..3

  for (int t = 0; t < NT; ++t) {
    // tile t's loads must have landed; keep 2 tiles in flight (never drain)
    if (t < NT - 2) {
      if constexpr (NREP == 4) asm volatile("s_waitcnt vmcnt(8)" ::: "memory");
      else                     asm volatile("s_waitcnt vmcnt(6)" ::: "memory");
    } else if (t == NT - 2) {
      if constexpr (NREP == 4) asm volatile("s_waitcnt vmcnt(4)" ::: "memory");
      else                     asm volatile("s_waitcnt vmcnt(3)" ::: "memory");
    } else {
      asm volatile("s_waitcnt vmcnt(0)" ::: "memory");
    }
    __builtin_amdgcn_s_barrier();
    // prefetch tile t+3 into buf (t+3)&3 == (t-1)&3: its reads finished at
    // iter t-1, before every wave's arrival at the barrier above -> WAR-safe.
    if (t + 3 < NT) {
      u16* Lb = lds + ((t + 3) & 3) * BUF;
      stageA(Ab, lda, (t + 3) * 32, Lb, tid);
      if constexpr (NREP == 4) stageA(Bb, ldb, (t + 3) * 32, Lb + ASZ, tid);
      else stageB128(Bb, ldb, (t + 3) * 32, Lb + ASZ, tid);
    }
    const u16* LAp = lds + (t & 3) * BUF;
    const u16* LBp = LAp + ASZ;
    bf16x8 af[8], bfr[NREP];
#pragma unroll
    for (int m = 0; m < 8; ++m) {
      const int R = wr + m * 16 + lr;
      af[m] = *(const bf16x8*)(LAp + R * 32 + ((cA ^ swz(R)) << 3));
    }
#pragma unroll
    for (int n = 0; n < NREP; ++n) {
      const int R = wc + n * 16 + lr;
      bfr[n] = *(const bf16x8*)(LBp + R * 32 + ((cA ^ swz(R)) << 3));
    }
    __builtin_amdgcn_s_setprio(1);
#pragma unroll
    for (int m = 0; m < 8; ++m)
#pragma unroll
      for (int n = 0; n < NREP; ++n)
        acc[m][n] = __builtin_amdgcn_mfma_f32_16x16x32_bf16(af[m], bfr[n],
                                                            acc[m][n], 0, 0, 0);
    __builtin_amdgcn_s_setprio(0);
  }

  // epilogue: C/D map col=lane&15, row=(lane>>4)*4+reg
  const int rr = (lane >> 4) << 2;
  // per-z params for EPI==1: z=0 reads Q/32 (needs x32 pre-bias) and scales
  // the output by es; z=1 reads K (no pre-scale), output unscaled.
  float ps = preScale, mul = 1.0f;
  if constexpr (EPI == 1) {
    ps = (z == 0) ? preScale : 1.0f;
    mul = (z == 0) ? esp[0] : 1.0f;
  }
#pragma unroll
  for (int m = 0; m < 8; ++m) {
#pragma unroll
    for (int n = 0; n < NREP; ++n) {
      const int col = (int)tN + wc + n * 16 + lr;
#pragma unroll
      for (int r = 0; r < 4; ++r) {
        const long long row = tM + wr + m * 16 + rr + r;
        const float v = acc[m][n][r];
        if constexpr (EPI == 0) {
          const int g = col >> 10, cc = col & 1023;
          if (g == 0)      ((u16*)C0)[row * 2048 + cc] = f2b((v + b0[cc]) * 0.03125f);
          else if (g == 1) ((u16*)C1)[row * 2048 + cc] = f2b(v + b1[cc]);
          else             ((u16*)C2)[row * 1024 + cc] = f2b(v + b2[cc]);
        } else if constexpr (EPI == 1) {
          const float tt = v * ps + b0[col];
          const float sg = 1.f / (1.f + __expf(-tt));
          ((u16*)C0)[z * sCz + row * ldc + col] = f2b(mul * cospif(sg));
        } else if constexpr (EPI == 2) {
          ((u16*)C0)[z * sCz + row * ldc + col] = f2b(v);
        } else if constexpr (EPI == 3) {
          ((float*)C0)[z * sCz + row * ldc + col] = v + b0[col];
        } else {
          ((float*)C0)[z * sCz + row * ldc + col] = v;
        }
      }
    }
  }
}

// row softmax over [8192][2048]: fp32 in-place + bf16 copy
__global__ __launch_bounds__(256) void softmax_rows(float* __restrict__ L,
                                                    u16* __restrict__ AB) {
  const long long row = blockIdx.x;
  float4* p4 = (float4*)(L + row * 2048);
  const int tid = threadIdx.x;
  float4 a = p4[tid], b = p4[tid + 256];
  float m = fmaxf(fmaxf(fmaxf(a.x, a.y), fmaxf(a.z, a.w)),
                  fmaxf(fmaxf(b.x, b.y), fmaxf(b.z, b.w)));
#pragma unroll
  for (int o = 32; o > 0; o >>= 1) m = fmaxf(m, __shfl_xor(m, o));
  __shared__ float rmax[4], rsum[4];
  const int wid = tid >> 6, lane = tid & 63;
  if (lane == 0) rmax[wid] = m;
  __syncthreads();
  m = fmaxf(fmaxf(rmax[0], rmax[1]), fmaxf(rmax[2], rmax[3]));
  a.x = __expf(a.x - m); a.y = __expf(a.y - m);
  a.z = __expf(a.z - m); a.w = __expf(a.w - m);
  b.x = __expf(b.x - m); b.y = __expf(b.y - m);
  b.z = __expf(b.z - m); b.w = __expf(b.w - m);
  float s = a.x + a.y + a.z + a.w + b.x + b.y + b.z + b.w;
#pragma unroll
  for (int o = 32; o > 0; o >>= 1) s += __shfl_xor(s, o);
  if (lane == 0) rsum[wid] = s;
  __syncthreads();
  s = rsum[0] + rsum[1] + rsum[2] + rsum[3];
  const float inv = 1.0f / s;
  a.x *= inv; a.y *= inv; a.z *= inv; a.w *= inv;
  b.x *= inv; b.y *= inv; b.z *= inv; b.w *= inv;
  p4[tid] = a;
  p4[tid + 256] = b;
  ushort4* o4 = (ushort4*)(AB + row * 2048);
  o4[tid]       = make_ushort4(f2b(a.x), f2b(a.y), f2b(a.z), f2b(a.w));
  o4[tid + 256] = make_ushort4(f2b(b.x), f2b(b.y), f2b(b.z), f2b(b.w));
}

__global__ __launch_bounds__(256) void cvt_x(const float* __restrict__ X,
                                             u16* __restrict__ XB) {
  const int i = blockIdx.x * 256 + threadIdx.x;
  float4 v = ((const float4*)X)[i];
  ((ushort4*)XB)[i] = make_ushort4(f2b(v.x), f2b(v.y), f2b(v.z), f2b(v.w));
}

// transpose+convert 5 weight matrices [1024,1024] f32 -> bf16 W^T
__global__ void cvt_w(const float* __restrict__ W0, const float* __restrict__ W1,
                      const float* __restrict__ W2, const float* __restrict__ W3,
                      const float* __restrict__ W4, u16* __restrict__ WT) {
  __shared__ float t[32][33];
  const int z = blockIdx.z;
  const float* W = (z == 0) ? W0 : (z == 1) ? W1 : (z == 2) ? W2 : (z == 3) ? W3 : W4;
  u16* D = WT + (long long)z * 1024 * 1024;
  const int c0 = blockIdx.x * 32, r0 = blockIdx.y * 32;
  const int tx = threadIdx.x, ty = threadIdx.y;
#pragma unroll
  for (int i = 0; i < 4; ++i)
    t[ty + i * 8][tx] = W[(long long)(r0 + ty + i * 8) * 1024 + c0 + tx];
  __syncthreads();
#pragma unroll
  for (int i = 0; i < 4; ++i)
    D[(long long)(c0 + ty + i * 8) * 1024 + r0 + tx] = f2b(t[tx][ty + i * 8]);
}

// Vb [8192,1024] bf16 -> VT [4][1024,2048] bf16
__global__ void transpose_v(const u16* __restrict__ Vb, u16* __restrict__ VT) {
  __shared__ u16 t[32][33];
  const int b = blockIdx.z;
  const u16* V = Vb + (long long)b * 2048 * 1024;
  u16* O = VT + (long long)b * 1024 * 2048;
  const int d0 = blockIdx.x * 32, s0 = blockIdx.y * 32;
  const int tx = threadIdx.x, ty = threadIdx.y;
#pragma unroll
  for (int i = 0; i < 4; ++i)
    t[ty + i * 8][tx] = V[(long long)(s0 + ty + i * 8) * 1024 + d0 + tx];
  __syncthreads();
#pragma unroll
  for (int i = 0; i < 4; ++i)
    O[(long long)(d0 + ty + i * 8) * 2048 + s0 + tx] = t[tx][ty + i * 8];
}

extern "C" void kernel_launch(void* const* d_in, const int* in_sizes, int n_in,
                              void* d_out, int out_size, void* d_ws,
                              size_t ws_size, hipStream_t stream) {
  const float* x  = (const float*)d_in[0];
  const float* Wq = (const float*)d_in[1];
  const float* bq = (const float*)d_in[2];
  const float* Wk = (const float*)d_in[3];
  const float* bk = (const float*)d_in[4];
  const float* Wv = (const float*)d_in[5];
  const float* bv = (const float*)d_in[6];
  const float* Wt = (const float*)d_in[7];
  const float* bt = (const float*)d_in[8];
  const float* Wo = (const float*)d_in[9];
  const float* bo = (const float*)d_in[10];
  const float* es = (const float*)d_in[11];

  char* ws = (char*)d_ws;
  u16* WT   = (u16*)(ws);               // 5x [1024,1024] bf16 (WqT,WkT,WvT,WtT,WoT)
  u16* XB   = (u16*)(ws + 10485760);    // [8192,1024] bf16; later AV
  u16* Qcat = (u16*)(ws + 27262976);    // [8192,2048] bf16: Q/32 | es*r_q ; later ATT
  u16* Kcat = Qcat + 16777216;          // [8192,2048] bf16: K | r_k
  u16* Vb   = (u16*)(ws + 94371840);    // [8192,1024] bf16
  u16* VT   = (u16*)(ws + 111149056);   // [4][1024,2048] bf16
  u16* WtT  = WT + 3 * 1048576;
  u16* WoT  = WT + 4 * 1048576;
  u16* ATT  = Qcat;
  u16* AV   = XB;

  float* outO = (float*)d_out;          // [4,2048,1024]
  float* outA = outO + 8388608;         // [4,2048,2048]

  cvt_x<<<8192, 256, 0, stream>>>(x, XB);
  cvt_w<<<dim3(32, 32, 5), dim3(32, 8), 0, stream>>>(Wq, Wk, Wv, Wt, Wo, WT);
  // QKV projection -> Qcat[:, :1024]=(Q+bq)/32, Kcat[:, :1024]=K, Vb=V
  g256<0, 4><<<dim3(12, 32, 1), 512, 0, stream>>>(
      XB, 1024, 0, WT, 1024, 0, Qcat, Kcat, Vb, 0, 0, 1024, bq, bk, bv, 1.f, nullptr);
  // theta (z=0: Q/32 -> es*r_q into Qcat[:,1024:] with ps=32;
  //        z=1: K    -> r_k   into Kcat[:,1024:] with ps=1)
  g256<1, 4><<<dim3(4, 32, 2), 512, 0, stream>>>(
      Qcat, 2048, 16777216LL, WtT, 1024, 0, Qcat + 1024, nullptr, nullptr,
      2048, 16777216LL, 1024, bt, nullptr, nullptr, 32.f, es);
  transpose_v<<<dim3(32, 64, 4), dim3(32, 8), 0, stream>>>(Vb, VT);
  // logits = Qcat @ Kcat^T (K=2048) per batch
  g256<4, 4><<<dim3(8, 8, 4), 512, 0, stream>>>(
      Qcat, 2048, 4194304LL, Kcat, 2048, 4194304LL, outA, nullptr, nullptr,
      2048, 4194304LL, 2048, nullptr, nullptr, nullptr, 1.f, nullptr);
  softmax_rows<<<8192, 256, 0, stream>>>(outA, ATT);
  // attn @ V
  g256<2, 2><<<dim3(8, 8, 4), 512, 0, stream>>>(
      ATT, 2048, 4194304LL, VT, 2048, 2097152LL, AV, nullptr, nullptr,
      1024, 2097152LL, 2048, nullptr, nullptr, nullptr, 1.f, nullptr);
  // output projection
  g256<3, 2><<<dim3(8, 32, 1), 512, 0, stream>>>(
      AV, 1024, 0, WoT, 1024, 0, outO, nullptr, nullptr,
      1024, 0, 1024, bo, nullptr, nullptr, 1.f, nullptr);
}